// Round 14
// baseline (1893.020 us; speedup 1.0000x reference)
//
#include <hip/hip_runtime.h>

// Problem: VOCAB=10000, EMB=100, T=80, UNITS=256, BATCH=4096 — ALL FP32 I/O.
// out = sigmoid(h2_T);  h_l,t = tanh(x_l,t @ Wl + h_l,t-1 @ Ul + bl)
#define BATCH 4096
#define TLEN  80
#define EMBD  100
#define UNITS 256
#define EMB_PAD 128            // emb K padded to 4 k-tiles of 32

typedef _Float16 f16;
typedef __attribute__((ext_vector_type(8))) _Float16 h8;   // 8 f16 = 4 VGPR MFMA A/B frag
typedef __attribute__((ext_vector_type(4))) float f32x4;   // MFMA C/D frag

__device__ __forceinline__ float fast_tanh(float x) {
  x = fminf(fmaxf(x, -15.f), 15.f);
  float e = __expf(-2.f * x);
  return (1.f - e) / (1.f + e);
}
__device__ __forceinline__ float fast_sigmoid(float x) {
  x = fminf(fmaxf(x, -30.f), 30.f);
  return 1.f / (1.f + __expf(-x));
}

// ---------------- workspace layout (3.02 MB; < 4 MB per-XCD L2 — r10 lesson:
// 6.9 MB hot set thrashed L2, 3.0 MB hits ~99.6%) ---------------------------
// B-frag layout (16x16x32, r7-verified, dtype-independent): lane holds
// B[k=quad*8+j][n=lane&15]; 8 contiguous f16 per (ktg,nt,lane) -> one dwordx4.
// ktg slots: W1 (K pad 128) = 0..3, U1 = 4..11, W2 = 12..19, U2 = 20..27.
#define KT_ALL 28
#define OFF_EHF ((size_t)0)
#define EHF_BYTES ((size_t)10000 * EMB_PAD * 2)             // 2,560,000
#define OFF_WF  EHF_BYTES
#define WF_BYTES ((size_t)KT_ALL * 16 * 64 * 8 * 2)         //   458,752
#define WS_NEED (OFF_WF + WF_BYTES)                          // 3,018,752 B

__device__ __forceinline__ size_t fidx(int ktg, int nt, int lane) {
  return (((size_t)ktg * 16 + nt) * 64 + lane) * 8;
}

// ---------------- precompute: weights -> swizzled fp16 B-frags (r10-verified)
__global__ __launch_bounds__(256) void k_split_w16(
    const float* __restrict__ W1, const float* __restrict__ U1,
    const float* __restrict__ W2, const float* __restrict__ U2,
    f16* __restrict__ wf)
{
  int gid = blockIdx.x * 256 + threadIdx.x;           // one per (ktg,nt,lane)
  if (gid >= KT_ALL * 16 * 64) return;
  int lane = gid & 63, nt = (gid >> 6) & 15, ktg = gid >> 10;
  const float* M; int Kact, ktl;
  if (ktg < 4)       { M = W1; Kact = EMBD;  ktl = ktg;      }
  else if (ktg < 12) { M = U1; Kact = UNITS; ktl = ktg - 4;  }
  else if (ktg < 20) { M = W2; Kact = UNITS; ktl = ktg - 12; }
  else               { M = U2; Kact = UNITS; ktl = ktg - 20; }
  int n = nt * 16 + (lane & 15);
  int kb = ktl * 32 + (lane >> 4) * 8;
  size_t base = fidx(ktg, nt, lane);
#pragma unroll
  for (int j = 0; j < 8; ++j) {
    int k = kb + j;
    wf[base + j] = (f16)((k < Kact) ? M[(size_t)k * UNITS + n] : 0.f);  // RNE
  }
}

// ---------------- precompute: emb -> padded fp16 (r10-verified) -------------
__global__ __launch_bounds__(256) void k_split_emb16(
    const float* __restrict__ emb, f16* __restrict__ ehf)
{
  int gid = blockIdx.x * 256 + threadIdx.x;
  if (gid >= 10000 * EMB_PAD) return;
  int row = gid >> 7, kk = gid & (EMB_PAD - 1);
  ehf[gid] = (f16)((kk < EMBD) ? emb[row * EMBD + kk] : 0.f);
}

#define MFMA16(A, B, C) __builtin_amdgcn_mfma_f32_16x16x32_f16(A, B, C, 0, 0, 0)

// store tanh result into next-step A-frag (single f16; layout r7-verified):
// elem (row=m, col=k): kt=col>>5, lane'=((col>>3)&3)*16+row, j'=col&7
__device__ __forceinline__ void store_frag1(f16* __restrict__ f, int col, int row, float v) {
  int a = (col >> 5) * 512 + (((col >> 3) & 3) * 16 + row) * 8 + (col & 7);
  f[a] = (f16)v;
}

// ---------------------------------------------------------------------------
// Main kernel v8: M=8 rows/block -> 512 blocks -> 2 INDEPENDENT blocks/CU.
// r13 showed matrix-pipe busy (63 us) ~= the 72 us MFMA floor: the other 410
// us is lockstep barrier serialization of one 16-wave block. Two co-resident
// blocks overlap each other's barrier drains (m114 co-schedule). Cost: A-tile
// rows 8..15 are dead (pollute only C rows 8..15, never read).
// Block = 512 thr = 8 waves; wave owns n-tiles {2w, 2w+1} (56 pinned B-frags
// ~224 VGPR; waves_per_eu(4,4) -> 512 budget at 4 waves/SIMD).
// LDS/block: f1+f2 = 32 KB; x2 blocks = 64 KB/CU.
// ---------------------------------------------------------------------------
__global__ __launch_bounds__(512)
__attribute__((amdgpu_waves_per_eu(4, 4)))
void rnn_m8(
    const int* __restrict__ idx, const f16* __restrict__ ehf,
    const f16* __restrict__ wf,
    const float* __restrict__ b1, const float* __restrict__ b2,
    float* __restrict__ out)
{
  __shared__ __align__(16) f16 f1[2][4096];   // [buf][kt*512 + lane*8 + j]
  __shared__ __align__(16) f16 f2[2][4096];

  const int tid  = threadIdx.x;
  const int lane = tid & 63;
  const int w    = tid >> 6;          // wave 0..7 -> n-tiles 2w, 2w+1
  const int m    = lane & 15;
  const int q    = lane >> 4;
  const int nt0  = 2 * w;
  const int col0 = nt0 * 16 + m;
  const int col1 = col0 + 16;
  const int b0   = blockIdx.x * 8;    // 8 batch rows per block

  const float b1c0 = b1[col0], b1c1 = b1[col1];
  const float b2c0 = b2[col0], b2c1 = b2[col1];
  const int mrow = (m < 8) ? m : (m - 8);           // rows 8..15 mirror 0..7 (dead)
  const int* tokp = idx + (size_t)(b0 + mrow) * TLEN;

  // -------- persistent weight fragments (56 = 224 VGPR), pinned ------------
  h8 Bx0[4], Bx1[4], Bu1a[8], Bu1b[8], Bw2a[8], Bw2b[8], Bu2a[8], Bu2b[8];
#pragma unroll
  for (int kt = 0; kt < 4; ++kt) {
    Bx0[kt] = *(const h8*)(wf + fidx(kt, nt0,     lane));
    Bx1[kt] = *(const h8*)(wf + fidx(kt, nt0 + 1, lane));
  }
#pragma unroll
  for (int kt = 0; kt < 8; ++kt) {
    Bu1a[kt] = *(const h8*)(wf + fidx(4  + kt, nt0,     lane));
    Bu1b[kt] = *(const h8*)(wf + fidx(4  + kt, nt0 + 1, lane));
    Bw2a[kt] = *(const h8*)(wf + fidx(12 + kt, nt0,     lane));
    Bw2b[kt] = *(const h8*)(wf + fidx(12 + kt, nt0 + 1, lane));
    Bu2a[kt] = *(const h8*)(wf + fidx(20 + kt, nt0,     lane));
    Bu2b[kt] = *(const h8*)(wf + fidx(20 + kt, nt0 + 1, lane));
  }
#pragma unroll
  for (int kt = 0; kt < 4; ++kt) { asm volatile("" : "+v"(Bx0[kt])); asm volatile("" : "+v"(Bx1[kt])); }
#pragma unroll
  for (int kt = 0; kt < 8; ++kt) {
    asm volatile("" : "+v"(Bu1a[kt])); asm volatile("" : "+v"(Bu1b[kt]));
    asm volatile("" : "+v"(Bw2a[kt])); asm volatile("" : "+v"(Bw2b[kt]));
    asm volatile("" : "+v"(Bu2a[kt])); asm volatile("" : "+v"(Bu2b[kt]));
  }

  // t=0 embedding fragment
  h8 Ax[4];
  {
    const f16* eh = ehf + (size_t)tokp[0] * EMB_PAD + q * 8;
#pragma unroll
    for (int kt = 0; kt < 4; ++kt) Ax[kt] = *(const h8*)(eh + kt * 32);
  }

  for (int i = tid; i < 4096; i += 512) {
    f1[0][i] = (f16)0.f; f1[1][i] = (f16)0.f;
    f2[0][i] = (f16)0.f; f2[1][i] = (f16)0.f;
  }
  __syncthreads();

  for (int t = 0; t < TLEN; ++t) {
    const int p = t & 1, qb = p ^ 1;

    // ---- layer 1: a1 = b1 + x_t @ W1 + h1_old @ U1  (4 indep chains) ----
    f32x4 a0A = (f32x4){0.f, 0.f, 0.f, 0.f}, a0B = a0A;   // n-tile 0
    f32x4 a1A = a0A, a1B = a0A;                           // n-tile 1
#pragma unroll
    for (int kt = 0; kt < 4; ++kt) {
      a0A = MFMA16(Ax[kt], Bx0[kt], a0A);
      a1A = MFMA16(Ax[kt], Bx1[kt], a1A);
    }
#pragma unroll
    for (int kt = 0; kt < 8; ++kt) {
      h8 ah = *(const h8*)&f1[p][kt * 512 + lane * 8];
      if (kt & 1) { a0A = MFMA16(ah, Bu1a[kt], a0A); a1A = MFMA16(ah, Bu1b[kt], a1A); }
      else        { a0B = MFMA16(ah, Bu1a[kt], a0B); a1B = MFMA16(ah, Bu1b[kt], a1B); }
    }
    if (q < 2) {                         // rows q*4+r in 0..7 are the valid ones
#pragma unroll
      for (int r = 0; r < 4; ++r) {
        int row = q * 4 + r;
        store_frag1(f1[qb], col0, row, fast_tanh(a0A[r] + a0B[r] + b1c0));
        store_frag1(f1[qb], col1, row, fast_tanh(a1A[r] + a1B[r] + b1c1));
      }
    }

    // ---- layer 2 pre-barrier half: h2_old @ U2 (independent of f1[qb]) ----
    f32x4 c0A = (f32x4){0.f, 0.f, 0.f, 0.f}, c0B = c0A;
    f32x4 c1A = c0A, c1B = c0A;
#pragma unroll
    for (int kt = 0; kt < 8; ++kt) {
      h8 ah = *(const h8*)&f2[p][kt * 512 + lane * 8];
      if (kt & 1) { c0A = MFMA16(ah, Bu2a[kt], c0A); c1A = MFMA16(ah, Bu2b[kt], c1A); }
      else        { c0B = MFMA16(ah, Bu2a[kt], c0B); c1B = MFMA16(ah, Bu2b[kt], c1B); }
    }
    __syncthreads();                           // barrier 1: f1[qb] visible

    // ---- layer 2 post-barrier half: h1_new @ W2 ----
#pragma unroll
    for (int kt = 0; kt < 8; ++kt) {
      h8 ah = *(const h8*)&f1[qb][kt * 512 + lane * 8];
      if (kt & 1) { c0A = MFMA16(ah, Bw2a[kt], c0A); c1A = MFMA16(ah, Bw2b[kt], c1A); }
      else        { c0B = MFMA16(ah, Bw2a[kt], c0B); c1B = MFMA16(ah, Bw2b[kt], c1B); }
    }
    // prefetch next step's embedding fragment (hidden under epilogue+barrier)
    if (t + 1 < TLEN) {
      const f16* eh = ehf + (size_t)tokp[t + 1] * EMB_PAD + q * 8;
#pragma unroll
      for (int kt = 0; kt < 4; ++kt) Ax[kt] = *(const h8*)(eh + kt * 32);
    }
    if (q < 2) {
#pragma unroll
      for (int r = 0; r < 4; ++r) {
        int row = q * 4 + r;
        float t0 = fast_tanh(c0A[r] + c0B[r] + b2c0);
        float t1 = fast_tanh(c1A[r] + c1B[r] + b2c1);
        store_frag1(f2[qb], col0, row, t0);
        store_frag1(f2[qb], col1, row, t1);
        if (t == TLEN - 1) {
          out[(size_t)(b0 + row) * UNITS + col0] = fast_sigmoid(t0);
          out[(size_t)(b0 + row) * UNITS + col1] = fast_sigmoid(t1);
        }
      }
    }
    __syncthreads();                           // barrier 2: f2[qb] visible
  }
}

// ---------------------------------------------------------------------------
extern "C" void kernel_launch(void* const* d_in, const int* in_sizes, int n_in,
                              void* d_out, int out_size, void* d_ws, size_t ws_size,
                              hipStream_t stream)
{
  const int*   idx = (const int*)d_in[0];
  const float* emb = (const float*)d_in[1];
  const float* W1  = (const float*)d_in[2];
  const float* U1  = (const float*)d_in[3];
  const float* b1  = (const float*)d_in[4];
  const float* W2  = (const float*)d_in[5];
  const float* U2  = (const float*)d_in[6];
  const float* b2  = (const float*)d_in[7];
  // d_in[8] (Wd), d_in[9] (bd) dead in the reference output.
  float* out = (float*)d_out;

  // WS_NEED = 3.02 MB < 6.04 MB proven available (r7); < 4 MB L2 per XCD.
  f16* ehf = (f16*)((char*)d_ws + OFF_EHF);
  f16* wf  = (f16*)((char*)d_ws + OFF_WF);
  k_split_emb16<<<(10000 * EMB_PAD + 255) / 256, 256, 0, stream>>>(emb, ehf);
  k_split_w16<<<(KT_ALL * 16 * 64 + 255) / 256, 256, 0, stream>>>(W1, U1, W2, U2, wf);
  rnn_m8<<<BATCH / 8, 512, 0, stream>>>(idx, ehf, wf, b1, b2, out);
}

// Round 16
// 716.086 us; speedup vs baseline: 2.6436x; 2.6436x over previous
//
#include <hip/hip_runtime.h>

// Problem: VOCAB=10000, EMB=100, T=80, UNITS=256, BATCH=4096 — ALL FP32 I/O.
// out = sigmoid(h2_T);  h_l,t = tanh(x_l,t @ Wl + h_l,t-1 @ Ul + bl)
#define BATCH 4096
#define TLEN  80
#define EMBD  100
#define UNITS 256
#define EMB_PAD 128            // emb K padded to 4 k-tiles of 32

typedef _Float16 f16;
typedef __attribute__((ext_vector_type(8))) _Float16 h8;   // 8 f16 = 4 VGPR MFMA A/B frag
typedef __attribute__((ext_vector_type(4))) float f32x4;   // MFMA C/D frag

__device__ __forceinline__ float fast_tanh(float x) {
  x = fminf(fmaxf(x, -15.f), 15.f);
  float e = __expf(-2.f * x);
  return (1.f - e) / (1.f + e);
}
__device__ __forceinline__ float fast_sigmoid(float x) {
  x = fminf(fmaxf(x, -30.f), 30.f);
  return 1.f / (1.f + __expf(-x));
}

// ---------------- workspace layout (3.02 MB; < 4 MB per-XCD L2) -------------
// B-frag layout (16x16x32, r7-verified): lane holds B[k=quad*8+j][n=lane&15];
// 8 contiguous f16 per (ktg,nt,lane). ktg: W1=0..3, U1=4..11, W2=12..19, U2=20..27.
#define KT_ALL 28
#define OFF_EHF ((size_t)0)
#define EHF_BYTES ((size_t)10000 * EMB_PAD * 2)             // 2,560,000
#define OFF_WF  EHF_BYTES
#define WF_BYTES ((size_t)KT_ALL * 16 * 64 * 8 * 2)         //   458,752
#define WS_NEED (OFF_WF + WF_BYTES)                          // 3,018,752 B

__device__ __forceinline__ size_t fidx(int ktg, int nt, int lane) {
  return (((size_t)ktg * 16 + nt) * 64 + lane) * 8;
}

// ---------------- precompute: weights -> swizzled fp16 B-frags (r10-verified)
__global__ __launch_bounds__(256) void k_split_w16(
    const float* __restrict__ W1, const float* __restrict__ U1,
    const float* __restrict__ W2, const float* __restrict__ U2,
    f16* __restrict__ wf)
{
  int gid = blockIdx.x * 256 + threadIdx.x;           // one per (ktg,nt,lane)
  if (gid >= KT_ALL * 16 * 64) return;
  int lane = gid & 63, nt = (gid >> 6) & 15, ktg = gid >> 10;
  const float* M; int Kact, ktl;
  if (ktg < 4)       { M = W1; Kact = EMBD;  ktl = ktg;      }
  else if (ktg < 12) { M = U1; Kact = UNITS; ktl = ktg - 4;  }
  else if (ktg < 20) { M = W2; Kact = UNITS; ktl = ktg - 12; }
  else               { M = U2; Kact = UNITS; ktl = ktg - 20; }
  int n = nt * 16 + (lane & 15);
  int kb = ktl * 32 + (lane >> 4) * 8;
  size_t base = fidx(ktg, nt, lane);
#pragma unroll
  for (int j = 0; j < 8; ++j) {
    int k = kb + j;
    wf[base + j] = (f16)((k < Kact) ? M[(size_t)k * UNITS + n] : 0.f);  // RNE
  }
}

// ---------------- precompute: emb -> padded fp16 (r10-verified) -------------
__global__ __launch_bounds__(256) void k_split_emb16(
    const float* __restrict__ emb, f16* __restrict__ ehf)
{
  int gid = blockIdx.x * 256 + threadIdx.x;
  if (gid >= 10000 * EMB_PAD) return;
  int row = gid >> 7, kk = gid & (EMB_PAD - 1);
  ehf[gid] = (f16)((kk < EMBD) ? emb[row * EMBD + kk] : 0.f);
}

#define MFMA16(A, B, C) __builtin_amdgcn_mfma_f32_16x16x32_f16(A, B, C, 0, 0, 0)

// store tanh result into A-frag layout (r7-verified):
// elem (row=m, col=k): kt=col>>5, lane'=((col>>3)&3)*16+row, j'=col&7
__device__ __forceinline__ void store_frag1(f16* __restrict__ f, int col, int row, float v) {
  int a = (col >> 5) * 512 + (((col >> 3) & 3) * 16 + row) * 8 + (col & 7);
  f[a] = (f16)v;
}

// ---------------------------------------------------------------------------
// v10: skewed layer-split pipeline with BLOCK-UNIFORM barriers.
// r15's race: __syncthreads() inside divergent wave-group branches (UB; two
// different static barriers). Fix: ONE loop, barrier at uniform point, only
// the barrier-free body diverges.
// Waves 0..7 (L1): interval i<T computes h1[i] from h1[i-1] (stable buffer).
// Waves 8..15 (L2): interval i>=1 computes h2[i-1] from h1[i-1], h2[i-2].
// 81 barriers total (vs r13's 160), L1/L2 phases overlap across wave groups.
// Frag pressure: SHARED 32-frag arrays (L1 uses 24+Ax, L2 all 32) = r13's
// proven-safe static pressure (r14's 56 spilled to scratch -> 6.5 GB HBM).
// Buffers: h1 write i&1 / read (i+1)&1; h2 read i&1 / write (i+1)&1;
// parity-1 buffers zeroed as the t=-1 state. Every RAW/WAR pair spans
// exactly one barrier.
// ---------------------------------------------------------------------------
__global__ __launch_bounds__(1024)
__attribute__((amdgpu_waves_per_eu(4, 4)))
void rnn_pipe2(
    const int* __restrict__ idx, const f16* __restrict__ ehf,
    const f16* __restrict__ wf,
    const float* __restrict__ b1, const float* __restrict__ b2,
    float* __restrict__ out)
{
  __shared__ __align__(16) f16 h1b[2][4096];   // [buf][kt*512 + lane*8 + j]
  __shared__ __align__(16) f16 h2b[2][4096];

  const int tid  = threadIdx.x;
  const int lane = tid & 63;
  const int w    = tid >> 6;          // wave 0..15
  const int m    = lane & 15;
  const int q    = lane >> 4;
  const int b0   = blockIdx.x * 16;
  const bool isL1 = (w < 8);
  const int g    = w & 7;             // group-local wave id -> n-tiles 2g, 2g+1
  const int nt0  = 2 * g;
  const int col0 = nt0 * 16 + m;
  const int col1 = col0 + 16;

  const float bc0 = isL1 ? b1[col0] : b2[col0];
  const float bc1 = isL1 ? b1[col1] : b2[col1];
  const int* tokp = idx + (size_t)(b0 + m) * TLEN;   // used by L1 only

  // -------- shared persistent frag arrays (32 frags = 128 regs, pinned) ----
  // L1: BA/BB = U1 (nt0/nt1), BC[0..3]/BD[0..3] = W1. L2: BA/BB = W2, BC/BD = U2.
  const int baseAB = isL1 ? 4 : 12;
  const int baseCD = isL1 ? 0 : 20;
  h8 BA[8], BB[8], BC[8], BD[8];
#pragma unroll
  for (int kt = 0; kt < 8; ++kt) {
    BA[kt] = *(const h8*)(wf + fidx(baseAB + kt, nt0,     lane));
    BB[kt] = *(const h8*)(wf + fidx(baseAB + kt, nt0 + 1, lane));
    int kk = baseCD + (isL1 ? (kt & 3) : kt);   // L1 dups W1 kts into 4..7 (unused)
    BC[kt] = *(const h8*)(wf + fidx(kk, nt0,     lane));
    BD[kt] = *(const h8*)(wf + fidx(kk, nt0 + 1, lane));
  }
#pragma unroll
  for (int kt = 0; kt < 8; ++kt) {
    asm volatile("" : "+v"(BA[kt])); asm volatile("" : "+v"(BB[kt]));
    asm volatile("" : "+v"(BC[kt])); asm volatile("" : "+v"(BD[kt]));
  }

  h8 Ax[4];                                     // L1 only: x[0] A-frag
  if (isL1) {
    const f16* eh = ehf + (size_t)tokp[0] * EMB_PAD + q * 8;
#pragma unroll
    for (int kt = 0; kt < 4; ++kt) Ax[kt] = *(const h8*)(eh + kt * 32);
  }

  // zero the "t = -1" (parity-1) buffers
  for (int i = tid; i < 4096; i += 1024) {
    h1b[1][i] = (f16)0.f;
    h2b[1][i] = (f16)0.f;
  }
  __syncthreads();                              // uniform init barrier

  for (int i = 0; i <= TLEN; ++i) {
    if (isL1) {
      if (i < TLEN) {
        const int pw = i & 1, pr = pw ^ 1;      // write h1[i], read h1[i-1]
        f32x4 a0A = (f32x4){0.f, 0.f, 0.f, 0.f}, a0B = a0A, a1A = a0A, a1B = a0A;
#pragma unroll
        for (int kt = 0; kt < 4; ++kt) {
          a0A = MFMA16(Ax[kt], BC[kt], a0A);    // x @ W1
          a1A = MFMA16(Ax[kt], BD[kt], a1A);
        }
#pragma unroll
        for (int kt = 0; kt < 8; ++kt) {
          h8 ah = *(const h8*)&h1b[pr][kt * 512 + lane * 8];   // h1[i-1]
          if (kt & 1) { a0A = MFMA16(ah, BA[kt], a0A); a1A = MFMA16(ah, BB[kt], a1A); }
          else        { a0B = MFMA16(ah, BA[kt], a0B); a1B = MFMA16(ah, BB[kt], a1B); }
        }
#pragma unroll
        for (int r = 0; r < 4; ++r) {
          int row = q * 4 + r;
          store_frag1(h1b[pw], col0, row, fast_tanh(a0A[r] + a0B[r] + bc0));
          store_frag1(h1b[pw], col1, row, fast_tanh(a1A[r] + a1B[r] + bc1));
        }
        if (i + 1 < TLEN) {                     // prefetch x[i+1] (global only)
          const f16* eh = ehf + (size_t)tokp[i + 1] * EMB_PAD + q * 8;
#pragma unroll
          for (int kt = 0; kt < 4; ++kt) Ax[kt] = *(const h8*)(eh + kt * 32);
        }
      }
    } else {
      if (i >= 1) {
        const int rh1 = (i + 1) & 1;            // h1[i-1]
        const int rh2 = i & 1;                  // h2[i-2]
        const int wh2 = (i + 1) & 1;            // h2[i-1]
        f32x4 c0A = (f32x4){0.f, 0.f, 0.f, 0.f}, c0B = c0A, c1A = c0A, c1B = c0A;
#pragma unroll
        for (int kt = 0; kt < 8; ++kt) {
          h8 ah = *(const h8*)&h1b[rh1][kt * 512 + lane * 8];  // h1[i-1] @ W2
          if (kt & 1) { c0A = MFMA16(ah, BA[kt], c0A); c1A = MFMA16(ah, BB[kt], c1A); }
          else        { c0B = MFMA16(ah, BA[kt], c0B); c1B = MFMA16(ah, BB[kt], c1B); }
        }
#pragma unroll
        for (int kt = 0; kt < 8; ++kt) {
          h8 ah = *(const h8*)&h2b[rh2][kt * 512 + lane * 8];  // h2[i-2] @ U2
          if (kt & 1) { c0A = MFMA16(ah, BC[kt], c0A); c1A = MFMA16(ah, BD[kt], c1A); }
          else        { c0B = MFMA16(ah, BC[kt], c0B); c1B = MFMA16(ah, BD[kt], c1B); }
        }
#pragma unroll
        for (int r = 0; r < 4; ++r) {
          int row = q * 4 + r;
          float t0 = fast_tanh(c0A[r] + c0B[r] + bc0);
          float t1 = fast_tanh(c1A[r] + c1B[r] + bc1);
          store_frag1(h2b[wh2], col0, row, t0);
          store_frag1(h2b[wh2], col1, row, t1);
          if (i == TLEN) {                      // h2[T-1]: final output
            out[(size_t)(b0 + row) * UNITS + col0] = fast_sigmoid(t0);
            out[(size_t)(b0 + row) * UNITS + col1] = fast_sigmoid(t1);
          }
        }
      }
    }
    __syncthreads();                            // BLOCK-UNIFORM interval barrier
  }
}

// ---------------------------------------------------------------------------
extern "C" void kernel_launch(void* const* d_in, const int* in_sizes, int n_in,
                              void* d_out, int out_size, void* d_ws, size_t ws_size,
                              hipStream_t stream)
{
  const int*   idx = (const int*)d_in[0];
  const float* emb = (const float*)d_in[1];
  const float* W1  = (const float*)d_in[2];
  const float* U1  = (const float*)d_in[3];
  const float* b1  = (const float*)d_in[4];
  const float* W2  = (const float*)d_in[5];
  const float* U2  = (const float*)d_in[6];
  const float* b2  = (const float*)d_in[7];
  // d_in[8] (Wd), d_in[9] (bd) dead in the reference output.
  float* out = (float*)d_out;

  // WS_NEED = 3.02 MB < 6.04 MB proven available (r7); < 4 MB L2 per XCD.
  f16* ehf = (f16*)((char*)d_ws + OFF_EHF);
  f16* wf  = (f16*)((char*)d_ws + OFF_WF);
  k_split_emb16<<<(10000 * EMB_PAD + 255) / 256, 256, 0, stream>>>(emb, ehf);
  k_split_w16<<<(KT_ALL * 16 * 64 + 255) / 256, 256, 0, stream>>>(W1, U1, W2, U2, wf);
  rnn_pipe2<<<BATCH / 16, 1024, 0, stream>>>(idx, ehf, wf, b1, b2, out);
}